// Round 7
// baseline (217.453 us; speedup 1.0000x reference)
//
#include <hip/hip_runtime.h>
#include <hip/hip_bf16.h>
#include <stdint.h>

// MoELoRALinear: out = x@W^T + b + sum_e softmax(x@rw^T)_e * SCALE * (x@A_e^T)@B_e^T
// M=8192, K=2048, N=2048, E=4, R=8. SCALE = 2.
#define M_ROWS 8192
#define KDIM   2048
#define NDIM   2048
#define SCALE_F 2.0f

typedef __attribute__((ext_vector_type(8))) short  bf16x8;
typedef __attribute__((ext_vector_type(4))) float  f32x4;
typedef __attribute__((ext_vector_type(8))) unsigned short u16x8;

__device__ __forceinline__ unsigned short f2bf(float f) {
    unsigned u = __float_as_uint(f);
    unsigned r = (u + 0x7fffu + ((u >> 16) & 1u)) >> 16;  // RNE
    return (unsigned short)r;
}

#define GLOAD_LDS16(gptr, lptr) \
    __builtin_amdgcn_global_load_lds((const __attribute__((address_space(1))) void*)(gptr), \
                                     (__attribute__((address_space(3))) void*)(lptr), 16, 0, 0)

// ---------------------------------------------------------------------------
// Kernel 0: pure stream x (fp32) -> xb (bf16). 8 elems/thread/iter.
// ---------------------------------------------------------------------------
__global__ __launch_bounds__(256) void k_xcast(
    const float* __restrict__ x, unsigned short* __restrict__ xb)
{
    const int t = blockIdx.x * 256 + threadIdx.x;
    const int nthr = gridDim.x * 256;
    for (int i = t; i < (M_ROWS * KDIM / 8); i += nthr) {
        float4 v0 = *(const float4*)(x + (size_t)i * 8);
        float4 v1 = *(const float4*)(x + (size_t)i * 8 + 4);
        u16x8 o = { f2bf(v0.x), f2bf(v0.y), f2bf(v0.z), f2bf(v0.w),
                    f2bf(v1.x), f2bf(v1.y), f2bf(v1.z), f2bf(v1.w) };
        *(u16x8*)(xb + (size_t)i * 8) = o;
    }
}

// ---------------------------------------------------------------------------
// Kernel 1: bw->wb bf16; pack W36[48][2048]=[A;rw;0]; Bm[e][o][r]->Bc[o][32].
// ---------------------------------------------------------------------------
__global__ __launch_bounds__(256) void k_wcast(
    const float* __restrict__ bw,
    const float* __restrict__ A,
    const float* __restrict__ rw,
    const float* __restrict__ Bm,
    unsigned short* __restrict__ wb,
    unsigned short* __restrict__ W36,
    unsigned short* __restrict__ Bc)
{
    const int t = blockIdx.x * 256 + threadIdx.x;
    const int nthr = gridDim.x * 256;

    for (int i = t; i < (NDIM * KDIM / 8); i += nthr) {
        float4 v0 = *(const float4*)(bw + (size_t)i * 8);
        float4 v1 = *(const float4*)(bw + (size_t)i * 8 + 4);
        u16x8 o = { f2bf(v0.x), f2bf(v0.y), f2bf(v0.z), f2bf(v0.w),
                    f2bf(v1.x), f2bf(v1.y), f2bf(v1.z), f2bf(v1.w) };
        *(u16x8*)(wb + (size_t)i * 8) = o;
    }
    if (t < 48 * 2048 / 8) {
        const int row = (t * 8) >> 11, col = (t * 8) & 2047;
        u16x8 o;
        if (row < 36) {
            const float* src = (row < 32) ? (A + (size_t)row * 2048 + col)
                                          : (rw + (size_t)(row - 32) * 2048 + col);
            float4 v0 = *(const float4*)(src);
            float4 v1 = *(const float4*)(src + 4);
            o = (u16x8){ f2bf(v0.x), f2bf(v0.y), f2bf(v0.z), f2bf(v0.w),
                         f2bf(v1.x), f2bf(v1.y), f2bf(v1.z), f2bf(v1.w) };
        } else {
            o = (u16x8){0, 0, 0, 0, 0, 0, 0, 0};
        }
        *(u16x8*)(W36 + (size_t)t * 8) = o;
    }
    if (t < 4 * 2048) {
        const int e = t >> 11, o = t & 2047;
        const float* src = Bm + ((size_t)e * 2048 + o) * 8;
        float4 v0 = *(const float4*)(src);
        float4 v1 = *(const float4*)(src + 4);
        u16x8 ov = { f2bf(v0.x), f2bf(v0.y), f2bf(v0.z), f2bf(v0.w),
                     f2bf(v1.x), f2bf(v1.y), f2bf(v1.z), f2bf(v1.w) };
        *(u16x8*)(Bc + (size_t)o * 32 + e * 8) = ov;
    }
}

// ---------------------------------------------------------------------------
// Kernel 2: skinny GEMM P[8192][48] = xb @ W36^T (bf16 in), K-split 4 waves,
// LDS partial-reduce, wave-0 softmax-gate epilogue -> Wg[M][32].
// grid = 512 x 256 (8 waves/CU).
// ---------------------------------------------------------------------------
__global__ __launch_bounds__(256) void k_proj(
    const unsigned short* __restrict__ xb,   // [8192][2048] bf16
    const unsigned short* __restrict__ W36,  // [48][2048]   bf16
    unsigned short* __restrict__ Wg)         // [8192][32]   bf16 (out)
{
    __shared__ float red[3][4][64][4];       // 12KB

    const int tid = threadIdx.x;
    const int l = tid & 63, w = tid >> 6;
    const int l15 = l & 15, l16h = l >> 4;
    const int row0 = blockIdx.x * 16;
    const int kbase = w * 512;

    const unsigned short* pa = xb + (size_t)(row0 + l15) * KDIM + kbase + l16h * 8;
    const unsigned short* pb0 = W36 + (size_t)(0 * 16 + l15) * KDIM + kbase + l16h * 8;
    const unsigned short* pb1 = W36 + (size_t)(1 * 16 + l15) * KDIM + kbase + l16h * 8;
    const unsigned short* pb2 = W36 + (size_t)(2 * 16 + l15) * KDIM + kbase + l16h * 8;

    f32x4 acc[3];
#pragma unroll
    for (int n = 0; n < 3; ++n) acc[n] = (f32x4){0.f, 0.f, 0.f, 0.f};

#pragma unroll 4
    for (int kt = 0; kt < 16; ++kt) {        // 16 x 32 = 512 k per wave
        bf16x8 a  = *(const bf16x8*)(pa  + kt * 32);
        bf16x8 b0 = *(const bf16x8*)(pb0 + kt * 32);
        bf16x8 b1 = *(const bf16x8*)(pb1 + kt * 32);
        bf16x8 b2 = *(const bf16x8*)(pb2 + kt * 32);
        acc[0] = __builtin_amdgcn_mfma_f32_16x16x32_bf16(a, b0, acc[0], 0, 0, 0);
        acc[1] = __builtin_amdgcn_mfma_f32_16x16x32_bf16(a, b1, acc[1], 0, 0, 0);
        acc[2] = __builtin_amdgcn_mfma_f32_16x16x32_bf16(a, b2, acc[2], 0, 0, 0);
    }

#pragma unroll
    for (int n = 0; n < 3; ++n)
#pragma unroll
        for (int j = 0; j < 4; ++j)
            red[n][w][l][j] = acc[n][j];
    __syncthreads();

    if (w == 0) {
#pragma unroll
        for (int n = 0; n < 3; ++n)
#pragma unroll
            for (int j = 0; j < 4; ++j)
                acc[n][j] = red[n][0][l][j] + red[n][1][l][j]
                          + red[n][2][l][j] + red[n][3][l][j];

        // gating. C/D: col=l&15, row=(l>>4)*4+j. acc[2] cols 32..35 = logits.
#pragma unroll
        for (int j = 0; j < 4; ++j) {
            const int base = l & 48;
            float lg0 = __shfl(acc[2][j], base + 0);
            float lg1 = __shfl(acc[2][j], base + 1);
            float lg2 = __shfl(acc[2][j], base + 2);
            float lg3 = __shfl(acc[2][j], base + 3);
            float mx = fmaxf(fmaxf(lg0, lg1), fmaxf(lg2, lg3));
            float e0 = __expf(lg0 - mx), e1 = __expf(lg1 - mx);
            float e2 = __expf(lg2 - mx), e3 = __expf(lg3 - mx);
            float inv = SCALE_F / (e0 + e1 + e2 + e3);
            float g0 = e0 * inv, g1 = e1 * inv, g2 = e2 * inv, g3 = e3 * inv;

            const int row = row0 + l16h * 4 + j;
#pragma unroll
            for (int n = 0; n < 2; ++n) {
                const int cn = n * 16 + l15;
                const int e = cn >> 3;
                float g = (e == 0) ? g0 : (e == 1) ? g1 : (e == 2) ? g2 : g3;
                Wg[(size_t)row * 32 + cn] = f2bf(g * acc[n][j]);
            }
        }
    }
}

// ---------------------------------------------------------------------------
// Kernel 3: 256x256 8-phase GEMM, schedule v5 (UNCHANGED from R6 — frozen
// for clean attribution of the prep restructure). BK=64, 512 thr, 128KB LDS.
// ---------------------------------------------------------------------------
#define RD_A(C, H) do { _Pragma("unroll") for (int mi = 0; mi < 4; ++mi) {     \
      afr[mi][0] = *(const bf16x8*)&S[(C)*16384 + (H)*8192 + mi*1024 + aoff0]; \
      afr[mi][1] = *(const bf16x8*)&S[(C)*16384 + (H)*8192 + mi*1024 + aoff1]; \
    } } while (0)

#define RD_B(C, H) do { _Pragma("unroll") for (int ni = 0; ni < 2; ++ni) {     \
      bfr[H][ni][0] = *(const bf16x8*)&Sb[(C)*16384 + (H)*8192 + ni*1024 + boff0]; \
      bfr[H][ni][1] = *(const bf16x8*)&Sb[(C)*16384 + (H)*8192 + ni*1024 + boff1]; \
    } } while (0)

#define MFMA16(AH, BH) do {                                                    \
    __builtin_amdgcn_s_setprio(1);                                             \
    _Pragma("unroll") for (int kk = 0; kk < 2; ++kk)                           \
      _Pragma("unroll") for (int mi = 0; mi < 4; ++mi)                         \
        _Pragma("unroll") for (int ni = 0; ni < 2; ++ni)                       \
          acc[(AH)*4+mi][(BH)*2+ni] = __builtin_amdgcn_mfma_f32_16x16x32_bf16( \
            afr[mi][kk], bfr[BH][ni][kk], acc[(AH)*4+mi][(BH)*2+ni], 0, 0, 0); \
    __builtin_amdgcn_s_setprio(0);                                             \
  } while (0)

#define BAR() __builtin_amdgcn_s_barrier()

__global__ __launch_bounds__(512, 2) void k_gemm(
    const unsigned short* __restrict__ xb,   // [M][2048] bf16
    const unsigned short* __restrict__ wb,   // [N][2048] bf16
    const unsigned short* __restrict__ Wg,   // [M][32]   bf16
    const unsigned short* __restrict__ Bc,   // [N][32]   bf16
    const float* __restrict__ bias,          // [N]
    float* __restrict__ out)                 // [M][N] fp32
{
    extern __shared__ unsigned short S[];    // 65536 shorts = 128KB
    unsigned short* Sb = S + 32768;

    const int tid = threadIdx.x;
    const int l = tid & 63, w = tid >> 6;
    const int l15 = l & 15, l16h = l >> 4, l7 = l & 7;
    const int wr = w >> 2, wc = w & 3;

    const int bid = blockIdx.x;
    const int tile = (bid & 7) * 32 + (bid >> 3);
    const int mt = tile >> 3, nt = tile & 7;
    const int m0 = mt * 256, n0 = nt * 256;

    const int aoff0 = (wr * 64 + l15) * 64 + ((l16h ^ l7) << 3);
    const int aoff1 = (wr * 64 + l15) * 64 + (((4 + l16h) ^ l7) << 3);
    const int boff0 = (wc * 32 + l15) * 64 + ((l16h ^ l7) << 3);
    const int boff1 = (wc * 32 + l15) * 64 + (((4 + l16h) ^ l7) << 3);

    const int st_row = w * 8 + (l >> 3);
    const int st_col = ((l & 7) ^ (l >> 3)) * 8;
    const unsigned short* gA0 = xb + (size_t)(m0 + st_row) * KDIM + st_col;
    const unsigned short* gB0 = wb + (size_t)(n0 + st_row) * KDIM + st_col;
    const int sw = w * 512;

    auto stageA = [&](int t, int h) {
        unsigned short* lp = S + ((t & 1) * 16384 + h * 8192 + sw);
        const unsigned short* gp = gA0 + (size_t)h * 128 * KDIM + t * 64;
        GLOAD_LDS16(gp, lp);
        GLOAD_LDS16(gp + (size_t)64 * KDIM, lp + 4096);
    };
    auto stageB = [&](int t, int h) {
        unsigned short* lp = Sb + ((t & 1) * 16384 + h * 8192 + sw);
        const unsigned short* gp = gB0 + (size_t)h * 128 * KDIM + t * 64;
        GLOAD_LDS16(gp, lp);
        GLOAD_LDS16(gp + (size_t)64 * KDIM, lp + 4096);
    };

    f32x4 acc[8][4];
#pragma unroll
    for (int m = 0; m < 8; ++m)
#pragma unroll
        for (int n = 0; n < 4; ++n)
            acc[m][n] = (f32x4){0.f, 0.f, 0.f, 0.f};
    bf16x8 afr[4][2];
    bf16x8 bfr[2][2][2];

    // prologue: T0 all 4 halves + B(1,h0) + A(1,h0); drain T0; pre-read B0(buf0)
    stageA(0, 0); stageA(0, 1); stageB(0, 0); stageB(0, 1);
    stageB(1, 0); stageA(1, 0);
    asm volatile("s_waitcnt vmcnt(4)" ::: "memory");
    BAR();
    RD_B(0, 0);

#pragma unroll 2
    for (int j = 0; j < 32; ++j) {
        const int c = j & 1, d = c ^ 1;
        RD_A(c, 0);
        if (j < 31) stageB(j + 1, 1);
        BAR(); MFMA16(0, 0); BAR();
        RD_B(c, 1);
        if (j < 31) stageA(j + 1, 1);
        BAR(); MFMA16(0, 1); BAR();
        RD_A(c, 1);
        if (j < 30) stageB(j + 2, 0);
        BAR(); MFMA16(1, 1); BAR();
        if (j < 30) stageA(j + 2, 0);
        if (j < 30)      { asm volatile("s_waitcnt vmcnt(4)" ::: "memory"); }
        else if (j == 30){ asm volatile("s_waitcnt vmcnt(0)" ::: "memory"); }
        BAR(); MFMA16(1, 0);
        if (j < 31) RD_B(d, 0);
        BAR();
    }

    // ---- fused LoRA: stage Wg[256][32] + Bc[256][32] linear, one K=32 step
    {
        const int lw_row = w * 16 + (l >> 2);
        const int lw_col = (l & 3) * 8;
        unsigned short* lpA = S + sw;
        const unsigned short* gpA = Wg + (size_t)(m0 + lw_row) * 32 + lw_col;
        GLOAD_LDS16(gpA, lpA);
        GLOAD_LDS16(gpA + (size_t)128 * 32, lpA + 4096);
        unsigned short* lpB = Sb + sw;
        const unsigned short* gpB = Bc + (size_t)(n0 + lw_row) * 32 + lw_col;
        GLOAD_LDS16(gpB, lpB);
        GLOAD_LDS16(gpB + (size_t)128 * 32, lpB + 4096);
    }
    asm volatile("s_waitcnt vmcnt(0)" ::: "memory");
    BAR();

#pragma unroll
    for (int m = 0; m < 8; ++m) {
        bf16x8 af = *(const bf16x8*)&S[((m >> 2) * 128 + wr * 64 + (m & 3) * 16 + l15) * 32 + l16h * 8];
#pragma unroll
        for (int n = 0; n < 4; ++n) {
            bf16x8 bf = *(const bf16x8*)&Sb[((n >> 1) * 128 + wc * 32 + (n & 1) * 16 + l15) * 32 + l16h * 8];
            acc[m][n] = __builtin_amdgcn_mfma_f32_16x16x32_bf16(af, bf, acc[m][n], 0, 0, 0);
        }
    }

    // ---- bias + store fp32 ----
#pragma unroll
    for (int n = 0; n < 4; ++n) {
        const int cn = n0 + (n >> 1) * 128 + wc * 32 + (n & 1) * 16 + l15;
        const float bv = bias[cn];
#pragma unroll
        for (int m = 0; m < 8; ++m) {
            const int rm = m0 + (m >> 2) * 128 + wr * 64 + (m & 3) * 16 + l16h * 4;
#pragma unroll
            for (int jj = 0; jj < 4; ++jj)
                out[(size_t)(rm + jj) * NDIM + cn] = acc[m][n][jj] + bv;
        }
    }
}

// ---------------------------------------------------------------------------
extern "C" void kernel_launch(void* const* d_in, const int* in_sizes, int n_in,
                              void* d_out, int out_size, void* d_ws, size_t ws_size,
                              hipStream_t stream) {
    const float* x      = (const float*)d_in[0];
    const float* base_w = (const float*)d_in[1];
    const float* base_b = (const float*)d_in[2];
    const float* A      = (const float*)d_in[3];
    const float* Bm     = (const float*)d_in[4];
    const float* rw     = (const float*)d_in[5];
    float* out = (float*)d_out;

    char* ws = (char*)d_ws;
    unsigned short* xb  = (unsigned short*)(ws);                            // 33,554,432 B
    unsigned short* wb  = (unsigned short*)(ws + 33554432);                 //  8,388,608 B
    unsigned short* W36 = (unsigned short*)(ws + 33554432 + 8388608);       //    196,608 B
    unsigned short* Wg  = (unsigned short*)(ws + 33554432 + 8388608 + 196608);           // 524,288 B
    unsigned short* Bc  = (unsigned short*)(ws + 33554432 + 8388608 + 196608 + 524288);  // 131,072 B

    // ORDER: xb and W36 must exist before k_proj; everything before k_gemm.
    k_xcast<<<dim3(1024), dim3(256), 0,      stream>>>(x, xb);
    k_wcast<<<dim3(256),  dim3(256), 0,      stream>>>(base_w, A, rw, Bm, wb, W36, Bc);
    k_proj <<<dim3(512),  dim3(256), 0,      stream>>>(xb, W36, Wg);
    k_gemm <<<dim3(256),  dim3(512), 131072, stream>>>(xb, wb, Wg, Bc, base_b, out);
}

// Round 8
// 210.085 us; speedup vs baseline: 1.0351x; 1.0351x over previous
//
#include <hip/hip_runtime.h>
#include <hip/hip_bf16.h>
#include <stdint.h>

// MoELoRALinear: out = x@W^T + b + sum_e softmax(x@rw^T)_e * SCALE * (x@A_e^T)@B_e^T
// M=8192, K=2048, N=2048, E=4, R=8. SCALE = 2.
#define M_ROWS 8192
#define KDIM   2048
#define NDIM   2048
#define SCALE_F 2.0f

typedef __attribute__((ext_vector_type(8))) short  bf16x8;
typedef __attribute__((ext_vector_type(4))) float  f32x4;
typedef __attribute__((ext_vector_type(8))) unsigned short u16x8;

__device__ __forceinline__ unsigned short f2bf(float f) {
    unsigned u = __float_as_uint(f);
    unsigned r = (u + 0x7fffu + ((u >> 16) & 1u)) >> 16;  // RNE
    return (unsigned short)r;
}

__device__ __forceinline__ bf16x8 cvt8(float4 v0, float4 v1) {
    return (bf16x8){ (short)f2bf(v0.x), (short)f2bf(v0.y),
                     (short)f2bf(v0.z), (short)f2bf(v0.w),
                     (short)f2bf(v1.x), (short)f2bf(v1.y),
                     (short)f2bf(v1.z), (short)f2bf(v1.w) };
}

#define GLOAD_LDS16(gptr, lptr) \
    __builtin_amdgcn_global_load_lds((const __attribute__((address_space(1))) void*)(gptr), \
                                     (__attribute__((address_space(3))) void*)(lptr), 16, 0, 0)

// ---------------------------------------------------------------------------
// Kernel 1: ALL prep in one launch. Per block (256 thr = 4 waves, 16 x-rows):
//  (a) grid-stride stream base_w -> wb bf16 (4 iters/thread)
//  (b) Bc scatter: Bm[e][o][r] -> Bc[o][e*8+r] bf16
//  (c) fused x-cast + rank-36 proj: wave w covers k in [w*512,(w+1)*512);
//      reads x fp32, converts, writes xb, MFMAs against A/rw (fp32, cvt
//      in-reg; rows 32..35 = router, rows 36+ = zero), LDS partial-reduce,
//      wave 0 softmax-gates -> Wg[M][32] = gate_e * SCALE * proj.
// grid = 512 x 256. No W36 buffer needed anymore.
// ---------------------------------------------------------------------------
__global__ __launch_bounds__(256) void k_prep(
    const float* __restrict__ x,      // [8192][2048]
    const float* __restrict__ bw,     // [2048][2048]
    const float* __restrict__ A,      // [32][2048]
    const float* __restrict__ rw,     // [4][2048]
    const float* __restrict__ Bm,     // [4][2048][8]
    unsigned short* __restrict__ xb,  // [8192][2048] bf16 (out)
    unsigned short* __restrict__ wb,  // [2048][2048] bf16 (out)
    unsigned short* __restrict__ Wg,  // [8192][32]   bf16 (out)
    unsigned short* __restrict__ Bc)  // [2048][32]   bf16 (out)
{
    __shared__ float red[3][4][64][4];       // 12KB

    const int tid = threadIdx.x;
    const int t = blockIdx.x * 256 + tid;
    const int nthr = gridDim.x * 256;

    // ---- (a) base_w stream ----
    for (int i = t; i < (NDIM * KDIM / 8); i += nthr) {
        float4 v0 = *(const float4*)(bw + (size_t)i * 8);
        float4 v1 = *(const float4*)(bw + (size_t)i * 8 + 4);
        *(bf16x8*)(wb + (size_t)i * 8) = cvt8(v0, v1);
    }
    // ---- (b) Bc scatter ----
    if (t < 4 * 2048) {
        const int e = t >> 11, o = t & 2047;
        const float* src = Bm + ((size_t)e * 2048 + o) * 8;
        float4 v0 = *(const float4*)(src);
        float4 v1 = *(const float4*)(src + 4);
        *(bf16x8*)(Bc + (size_t)o * 32 + e * 8) = cvt8(v0, v1);
    }

    // ---- (c) fused x-cast + proj ----
    const int l = tid & 63, w = tid >> 6;
    const int l15 = l & 15, l16h = l >> 4;
    const int row0 = blockIdx.x * 16;
    const int kbase = w * 512;

    const float* pa  = x  + (size_t)(row0 + l15) * KDIM + kbase + l16h * 8;
    unsigned short* pxb = xb + (size_t)(row0 + l15) * KDIM + kbase + l16h * 8;
    const float* pb0 = A  + (size_t)(l15)      * KDIM + kbase + l16h * 8;  // rows 0..15
    const float* pb1 = A  + (size_t)(16 + l15) * KDIM + kbase + l16h * 8;  // rows 16..31
    const float* pb2 = rw + (size_t)(l15 & 3)  * KDIM + kbase + l16h * 8;  // rows 32..35 (wrap)
    const bool b2live = (l15 < 4);

    f32x4 acc[3];
#pragma unroll
    for (int n = 0; n < 3; ++n) acc[n] = (f32x4){0.f, 0.f, 0.f, 0.f};

#pragma unroll 4
    for (int kt = 0; kt < 16; ++kt) {        // 16 x 32 = 512 k per wave
        float4 xa0 = *(const float4*)(pa + kt * 32);
        float4 xa1 = *(const float4*)(pa + kt * 32 + 4);
        bf16x8 a = cvt8(xa0, xa1);
        *(bf16x8*)(pxb + kt * 32) = a;

        float4 w00 = *(const float4*)(pb0 + kt * 32);
        float4 w01 = *(const float4*)(pb0 + kt * 32 + 4);
        float4 w10 = *(const float4*)(pb1 + kt * 32);
        float4 w11 = *(const float4*)(pb1 + kt * 32 + 4);
        float4 w20 = *(const float4*)(pb2 + kt * 32);
        float4 w21 = *(const float4*)(pb2 + kt * 32 + 4);
        if (!b2live) { w20 = (float4){0,0,0,0}; w21 = (float4){0,0,0,0}; }

        bf16x8 b0 = cvt8(w00, w01);
        bf16x8 b1 = cvt8(w10, w11);
        bf16x8 b2 = cvt8(w20, w21);
        acc[0] = __builtin_amdgcn_mfma_f32_16x16x32_bf16(a, b0, acc[0], 0, 0, 0);
        acc[1] = __builtin_amdgcn_mfma_f32_16x16x32_bf16(a, b1, acc[1], 0, 0, 0);
        acc[2] = __builtin_amdgcn_mfma_f32_16x16x32_bf16(a, b2, acc[2], 0, 0, 0);
    }

#pragma unroll
    for (int n = 0; n < 3; ++n)
#pragma unroll
        for (int j = 0; j < 4; ++j)
            red[n][w][l][j] = acc[n][j];
    __syncthreads();

    if (w == 0) {
#pragma unroll
        for (int n = 0; n < 3; ++n)
#pragma unroll
            for (int j = 0; j < 4; ++j)
                acc[n][j] = red[n][0][l][j] + red[n][1][l][j]
                          + red[n][2][l][j] + red[n][3][l][j];

        // gating. C/D: col=l&15, row=(l>>4)*4+j. acc[2] cols 32..35 = logits.
#pragma unroll
        for (int j = 0; j < 4; ++j) {
            const int base = l & 48;
            float lg0 = __shfl(acc[2][j], base + 0);
            float lg1 = __shfl(acc[2][j], base + 1);
            float lg2 = __shfl(acc[2][j], base + 2);
            float lg3 = __shfl(acc[2][j], base + 3);
            float mx = fmaxf(fmaxf(lg0, lg1), fmaxf(lg2, lg3));
            float e0 = __expf(lg0 - mx), e1 = __expf(lg1 - mx);
            float e2 = __expf(lg2 - mx), e3 = __expf(lg3 - mx);
            float inv = SCALE_F / (e0 + e1 + e2 + e3);
            float g0 = e0 * inv, g1 = e1 * inv, g2 = e2 * inv, g3 = e3 * inv;

            const int row = row0 + l16h * 4 + j;
#pragma unroll
            for (int n = 0; n < 2; ++n) {
                const int cn = n * 16 + l15;
                const int e = cn >> 3;
                float g = (e == 0) ? g0 : (e == 1) ? g1 : (e == 2) ? g2 : g3;
                Wg[(size_t)row * 32 + cn] = f2bf(g * acc[n][j]);
            }
        }
    }
}

// ---------------------------------------------------------------------------
// Kernel 2: 256x256 8-phase GEMM, schedule v5 (FROZEN — identical to R6/R7).
// BK=64, 512 thr, 128KB LDS.
// ---------------------------------------------------------------------------
#define RD_A(C, H) do { _Pragma("unroll") for (int mi = 0; mi < 4; ++mi) {     \
      afr[mi][0] = *(const bf16x8*)&S[(C)*16384 + (H)*8192 + mi*1024 + aoff0]; \
      afr[mi][1] = *(const bf16x8*)&S[(C)*16384 + (H)*8192 + mi*1024 + aoff1]; \
    } } while (0)

#define RD_B(C, H) do { _Pragma("unroll") for (int ni = 0; ni < 2; ++ni) {     \
      bfr[H][ni][0] = *(const bf16x8*)&Sb[(C)*16384 + (H)*8192 + ni*1024 + boff0]; \
      bfr[H][ni][1] = *(const bf16x8*)&Sb[(C)*16384 + (H)*8192 + ni*1024 + boff1]; \
    } } while (0)

#define MFMA16(AH, BH) do {                                                    \
    __builtin_amdgcn_s_setprio(1);                                             \
    _Pragma("unroll") for (int kk = 0; kk < 2; ++kk)                           \
      _Pragma("unroll") for (int mi = 0; mi < 4; ++mi)                         \
        _Pragma("unroll") for (int ni = 0; ni < 2; ++ni)                       \
          acc[(AH)*4+mi][(BH)*2+ni] = __builtin_amdgcn_mfma_f32_16x16x32_bf16( \
            afr[mi][kk], bfr[BH][ni][kk], acc[(AH)*4+mi][(BH)*2+ni], 0, 0, 0); \
    __builtin_amdgcn_s_setprio(0);                                             \
  } while (0)

#define BAR() __builtin_amdgcn_s_barrier()

__global__ __launch_bounds__(512, 2) void k_gemm(
    const unsigned short* __restrict__ xb,   // [M][2048] bf16
    const unsigned short* __restrict__ wb,   // [N][2048] bf16
    const unsigned short* __restrict__ Wg,   // [M][32]   bf16
    const unsigned short* __restrict__ Bc,   // [N][32]   bf16
    const float* __restrict__ bias,          // [N]
    float* __restrict__ out)                 // [M][N] fp32
{
    extern __shared__ unsigned short S[];    // 65536 shorts = 128KB
    unsigned short* Sb = S + 32768;

    const int tid = threadIdx.x;
    const int l = tid & 63, w = tid >> 6;
    const int l15 = l & 15, l16h = l >> 4, l7 = l & 7;
    const int wr = w >> 2, wc = w & 3;

    const int bid = blockIdx.x;
    const int tile = (bid & 7) * 32 + (bid >> 3);
    const int mt = tile >> 3, nt = tile & 7;
    const int m0 = mt * 256, n0 = nt * 256;

    const int aoff0 = (wr * 64 + l15) * 64 + ((l16h ^ l7) << 3);
    const int aoff1 = (wr * 64 + l15) * 64 + (((4 + l16h) ^ l7) << 3);
    const int boff0 = (wc * 32 + l15) * 64 + ((l16h ^ l7) << 3);
    const int boff1 = (wc * 32 + l15) * 64 + (((4 + l16h) ^ l7) << 3);

    const int st_row = w * 8 + (l >> 3);
    const int st_col = ((l & 7) ^ (l >> 3)) * 8;
    const unsigned short* gA0 = xb + (size_t)(m0 + st_row) * KDIM + st_col;
    const unsigned short* gB0 = wb + (size_t)(n0 + st_row) * KDIM + st_col;
    const int sw = w * 512;

    auto stageA = [&](int t, int h) {
        unsigned short* lp = S + ((t & 1) * 16384 + h * 8192 + sw);
        const unsigned short* gp = gA0 + (size_t)h * 128 * KDIM + t * 64;
        GLOAD_LDS16(gp, lp);
        GLOAD_LDS16(gp + (size_t)64 * KDIM, lp + 4096);
    };
    auto stageB = [&](int t, int h) {
        unsigned short* lp = Sb + ((t & 1) * 16384 + h * 8192 + sw);
        const unsigned short* gp = gB0 + (size_t)h * 128 * KDIM + t * 64;
        GLOAD_LDS16(gp, lp);
        GLOAD_LDS16(gp + (size_t)64 * KDIM, lp + 4096);
    };

    f32x4 acc[8][4];
#pragma unroll
    for (int m = 0; m < 8; ++m)
#pragma unroll
        for (int n = 0; n < 4; ++n)
            acc[m][n] = (f32x4){0.f, 0.f, 0.f, 0.f};
    bf16x8 afr[4][2];
    bf16x8 bfr[2][2][2];

    stageA(0, 0); stageA(0, 1); stageB(0, 0); stageB(0, 1);
    stageB(1, 0); stageA(1, 0);
    asm volatile("s_waitcnt vmcnt(4)" ::: "memory");
    BAR();
    RD_B(0, 0);

#pragma unroll 2
    for (int j = 0; j < 32; ++j) {
        const int c = j & 1, d = c ^ 1;
        RD_A(c, 0);
        if (j < 31) stageB(j + 1, 1);
        BAR(); MFMA16(0, 0); BAR();
        RD_B(c, 1);
        if (j < 31) stageA(j + 1, 1);
        BAR(); MFMA16(0, 1); BAR();
        RD_A(c, 1);
        if (j < 30) stageB(j + 2, 0);
        BAR(); MFMA16(1, 1); BAR();
        if (j < 30) stageA(j + 2, 0);
        if (j < 30)      { asm volatile("s_waitcnt vmcnt(4)" ::: "memory"); }
        else if (j == 30){ asm volatile("s_waitcnt vmcnt(0)" ::: "memory"); }
        BAR(); MFMA16(1, 0);
        if (j < 31) RD_B(d, 0);
        BAR();
    }

    {
        const int lw_row = w * 16 + (l >> 2);
        const int lw_col = (l & 3) * 8;
        unsigned short* lpA = S + sw;
        const unsigned short* gpA = Wg + (size_t)(m0 + lw_row) * 32 + lw_col;
        GLOAD_LDS16(gpA, lpA);
        GLOAD_LDS16(gpA + (size_t)128 * 32, lpA + 4096);
        unsigned short* lpB = Sb + sw;
        const unsigned short* gpB = Bc + (size_t)(n0 + lw_row) * 32 + lw_col;
        GLOAD_LDS16(gpB, lpB);
        GLOAD_LDS16(gpB + (size_t)128 * 32, lpB + 4096);
    }
    asm volatile("s_waitcnt vmcnt(0)" ::: "memory");
    BAR();

#pragma unroll
    for (int m = 0; m < 8; ++m) {
        bf16x8 af = *(const bf16x8*)&S[((m >> 2) * 128 + wr * 64 + (m & 3) * 16 + l15) * 32 + l16h * 8];
#pragma unroll
        for (int n = 0; n < 4; ++n) {
            bf16x8 bf = *(const bf16x8*)&Sb[((n >> 1) * 128 + wc * 32 + (n & 1) * 16 + l15) * 32 + l16h * 8];
            acc[m][n] = __builtin_amdgcn_mfma_f32_16x16x32_bf16(af, bf, acc[m][n], 0, 0, 0);
        }
    }

#pragma unroll
    for (int n = 0; n < 4; ++n) {
        const int cn = n0 + (n >> 1) * 128 + wc * 32 + (n & 1) * 16 + l15;
        const float bv = bias[cn];
#pragma unroll
        for (int m = 0; m < 8; ++m) {
            const int rm = m0 + (m >> 2) * 128 + wr * 64 + (m & 3) * 16 + l16h * 4;
#pragma unroll
            for (int jj = 0; jj < 4; ++jj)
                out[(size_t)(rm + jj) * NDIM + cn] = acc[m][n][jj] + bv;
        }
    }
}

// ---------------------------------------------------------------------------
extern "C" void kernel_launch(void* const* d_in, const int* in_sizes, int n_in,
                              void* d_out, int out_size, void* d_ws, size_t ws_size,
                              hipStream_t stream) {
    const float* x      = (const float*)d_in[0];
    const float* base_w = (const float*)d_in[1];
    const float* base_b = (const float*)d_in[2];
    const float* A      = (const float*)d_in[3];
    const float* Bm     = (const float*)d_in[4];
    const float* rw     = (const float*)d_in[5];
    float* out = (float*)d_out;

    char* ws = (char*)d_ws;
    unsigned short* xb = (unsigned short*)(ws);                       // 33,554,432 B
    unsigned short* wb = (unsigned short*)(ws + 33554432);            //  8,388,608 B
    unsigned short* Wg = (unsigned short*)(ws + 33554432 + 8388608);  //    524,288 B
    unsigned short* Bc = (unsigned short*)(ws + 33554432 + 8388608 + 524288);  // 131,072 B

    k_prep<<<dim3(512), dim3(256), 0,      stream>>>(x, base_w, A, rw, Bm, xb, wb, Wg, Bc);
    k_gemm<<<dim3(256), dim3(512), 131072, stream>>>(xb, wb, Wg, Bc, base_b, out);
}